// Round 5
// baseline (420.675 us; speedup 1.0000x reference)
//
#include <hip/hip_runtime.h>
#include <float.h>
#include <stdint.h>

#define TPB_H 1024              // histogram kernel block
#define TPB_G 1024              // gather kernel block
#define TPB_S 512               // sampler kernel block (8 waves)
#define NB 2048
#define NS 4                    // row-parts for hist/gather kernels (4*128 = 512 blocks)
#define CAND_CAP 2048
#define KEPT_CAP 4096
#define MAXLEV 6
#define NW_H (TPB_H / 64)
#define NW_S (TPB_S / 64)
#define FLO (-16.0f)
#define FSC ((float)NB / 32.0f)  // 64 bins per unit over [-16,16)

// Monotone, clamped linear binning — must be bit-identical across all passes.
__device__ __forceinline__ int bin_of(float x, float lo, float sc) {
  float bf = (x - lo) * sc;
  if (!(bf > 0.0f)) return 0;                 // also catches NaN
  if (bf >= (float)(NB - 1)) return NB - 1;
  return (int)bf;
}

__device__ __forceinline__ double wsum_d(double v) {
#pragma unroll
  for (int o = 32; o > 0; o >>= 1) v += __shfl_xor(v, o);
  return v;
}
__device__ __forceinline__ int wsum_i(int v) {
#pragma unroll
  for (int o = 32; o > 0; o >>= 1) v += __shfl_xor(v, o);
  return v;
}
__device__ __forceinline__ float wmax_f(float v) {
#pragma unroll
  for (int o = 32; o > 0; o >>= 1) v = fmaxf(v, __shfl_xor(v, o));
  return v;
}

// ---- sampler-block (TPB_S) reductions/scans ----
__device__ __forceinline__ double blk_sum_d(double v, double* sred, double* out) {
  v = wsum_d(v);
  __syncthreads();
  if ((threadIdx.x & 63) == 0) sred[threadIdx.x >> 6] = v;
  __syncthreads();
  if (threadIdx.x == 0) {
    double t = 0.0;
#pragma unroll
    for (int i = 0; i < NW_S; i++) t += sred[i];
    *out = t;
  }
  __syncthreads();
  return *out;
}

__device__ __forceinline__ int blk_sum_i(int v, int* sredi, int* out) {
  v = wsum_i(v);
  __syncthreads();
  if ((threadIdx.x & 63) == 0) sredi[threadIdx.x >> 6] = v;
  __syncthreads();
  if (threadIdx.x == 0) {
    int t = 0;
#pragma unroll
    for (int i = 0; i < NW_S; i++) t += sredi[i];
    *out = t;
  }
  __syncthreads();
  return *out;
}

// exclusive f64 block prefix: wave shuffle-scan + 8-entry aggregate scan (3 barriers)
__device__ __forceinline__ double blk_exscan_d(double v, double* sw, double* sw2) {
  const int tid = threadIdx.x;
  const int lane = tid & 63, wid = tid >> 6;
  __syncthreads();          // protect sw/sw2 reuse against preceding readers
  double incl = v;
#pragma unroll
  for (int o = 1; o < 64; o <<= 1) {
    double t = __shfl_up(incl, o);
    if (lane >= o) incl += t;
  }
  if (lane == 63) sw[wid] = incl;
  __syncthreads();
  if (tid == 0) {
    double acc = 0.0;
#pragma unroll
    for (int i = 0; i < NW_S; i++) { double t = sw[i]; sw2[i] = acc; acc += t; }
  }
  __syncthreads();
  return sw2[wid] + (incl - v);
}

// wave 0: given merged hist[NB] (desc scan from top) and rank k, find the bin
// holding the k-th largest, its count, and the within-bin rank kk (from top).
__device__ __forceinline__ void locate_kbin(const int* hist, int k,
                                            int* s_bin, int* s_kk, int* s_cntbin) {
  if (threadIdx.x < 64) {
    const int l = threadIdx.x;
    const int b0 = NB - (l + 1) * (NB / 64);   // lane 0 covers highest bins
    int c = 0;
#pragma unroll
    for (int j = 0; j < NB / 64; j++) c += hist[b0 + j];
    int incl = c;
#pragma unroll
    for (int o = 1; o < 64; o <<= 1) {
      int t2 = __shfl_up(incl, o);
      if (l >= o) incl += t2;
    }
    const int pref = incl - c;  // count in strictly-higher chunks
    if (pref < k && k <= pref + c) {
      int rem = k - pref;
      for (int j = NB / 64 - 1; j >= 0; j--) {
        const int h = hist[b0 + j];
        if (rem <= h) { *s_bin = b0 + j; *s_cntbin = h; *s_kk = rem; break; }
        rem -= h;
      }
    }
  }
}

// decode top_ks[row]: reference dtype int64, but harness may hand int32.
__device__ __forceinline__ int decode_k(const void* topks_raw, int row, int B, int V) {
  const int* ip = (const int*)topks_raw;
  const bool is64 = (B < 2) || (ip[1] == 0);
  long long kraw = is64 ? ((const long long*)topks_raw)[row] : (long long)ip[row];
  long long kidx = kraw - 1;
  if (kidx < 0) kidx = 0;
  if (kidx > (long long)(V - 1)) kidx = (long long)(V - 1);
  return (int)kidx + 1;
}

// Iterate a row; lv = raw logit, gi = global index. V4 is the vec4-covered prefix.
#define ROW_LOOP(...)                                                                  \
  do {                                                                                 \
    for (int i0_ = tid * 4; i0_ < V4; i0_ += TPB_S * 4) {                              \
      const float4 v4_ = *reinterpret_cast<const float4*>(lr + i0_);                   \
      { const float lv = v4_.x; const int gi = i0_ + 0; (void)gi; __VA_ARGS__ }        \
      { const float lv = v4_.y; const int gi = i0_ + 1; (void)gi; __VA_ARGS__ }        \
      { const float lv = v4_.z; const int gi = i0_ + 2; (void)gi; __VA_ARGS__ }        \
      { const float lv = v4_.w; const int gi = i0_ + 3; (void)gi; __VA_ARGS__ }        \
    }                                                                                  \
    for (int gi = V4 + tid; gi < V; gi += TPB_S) {                                     \
      const float lv = lr[gi]; (void)gi; __VA_ARGS__                                   \
    }                                                                                  \
  } while (0)

// ---------------- kernel 1: per (row, part) fixed-bin histogram + partial max ----
extern "C" __global__ void __launch_bounds__(TPB_H) hist_max_kernel(
    const float* __restrict__ logits, int V,
    int* __restrict__ ws_hist, float* __restrict__ ws_max,
    int* __restrict__ kept_cnt, int* __restrict__ cand_cnt, int zeroCnts) {
  __shared__ int hist[NB];
  __shared__ float sredf[NW_H];
  const int tid = threadIdx.x;
  const int row = blockIdx.x / NS;
  const int part = blockIdx.x % NS;
  const float* lr = logits + (size_t)row * (size_t)V;
  const int start = (int)(((long long)V * part) / NS);
  const int end = (int)(((long long)V * (part + 1)) / NS);
  const int cnt = end - start;

  if (zeroCnts && part == 0 && tid == 0) { kept_cnt[row] = 0; cand_cnt[row] = 0; }

  for (int i = tid; i < NB; i += TPB_H) hist[i] = 0;
  __syncthreads();

  float mx = -FLT_MAX;
  const int c4 = ((start & 3) == 0) ? (cnt & ~3) : 0;
  for (int i0 = tid * 4; i0 < c4; i0 += TPB_H * 4) {
    const float4 v4 = *reinterpret_cast<const float4*>(lr + start + i0);
    mx = fmaxf(mx, v4.x); atomicAdd(&hist[bin_of(v4.x, FLO, FSC)], 1);
    mx = fmaxf(mx, v4.y); atomicAdd(&hist[bin_of(v4.y, FLO, FSC)], 1);
    mx = fmaxf(mx, v4.z); atomicAdd(&hist[bin_of(v4.z, FLO, FSC)], 1);
    mx = fmaxf(mx, v4.w); atomicAdd(&hist[bin_of(v4.w, FLO, FSC)], 1);
  }
  for (int i = c4 + tid; i < cnt; i += TPB_H) {
    const float lv = lr[start + i];
    mx = fmaxf(mx, lv); atomicAdd(&hist[bin_of(lv, FLO, FSC)], 1);
  }

  mx = wmax_f(mx);
  __syncthreads();
  if ((tid & 63) == 0) sredf[tid >> 6] = mx;
  __syncthreads();
  if (tid == 0) {
    float t = sredf[0];
    for (int i = 1; i < NW_H; i++) t = fmaxf(t, sredf[i]);
    ws_max[blockIdx.x] = t;
  }
  __syncthreads();
  int* dst = ws_hist + (size_t)blockIdx.x * NB;
  for (int i = tid; i < NB; i += TPB_H) dst[i] = hist[i];
}

// ---------------- kernel 2: per (row, part) gather into global kept/cand bufs ----
extern "C" __global__ void __launch_bounds__(TPB_G) gather_kernel(
    const float* __restrict__ logits, const void* __restrict__ topks_raw,
    int V, int B, const int* __restrict__ ws_hist,
    int* __restrict__ kept_cnt, int* __restrict__ cand_cnt,
    float* __restrict__ kept_val_g, int* __restrict__ kept_idx_g,
    float* __restrict__ cand_val_g, int* __restrict__ cand_idx_g) {
  __shared__ int hist[NB];
  __shared__ int s_bin, s_kk, s_cntbin;
  const int tid = threadIdx.x;
  const int row = blockIdx.x / NS;
  const int part = blockIdx.x % NS;
  const int k = decode_k(topks_raw, row, B, V);

  // merge the NS part-histograms for this row (redundant per part-block, cheap)
  for (int i = tid; i < NB; i += TPB_G) {
    int t = 0;
#pragma unroll
    for (int p = 0; p < NS; p++) t += ws_hist[(size_t)(row * NS + p) * NB + i];
    hist[i] = t;
  }
  __syncthreads();
  locate_kbin(hist, k, &s_bin, &s_kk, &s_cntbin);
  __syncthreads();
  const int kbin = s_bin;

  const float* lr = logits + (size_t)row * (size_t)V;
  const int start = (int)(((long long)V * part) / NS);
  const int end = (int)(((long long)V * (part + 1)) / NS);
  const int cnt = end - start;
  float* kv = kept_val_g + (size_t)row * KEPT_CAP;
  int* ki = kept_idx_g + (size_t)row * KEPT_CAP;
  float* cv = cand_val_g + (size_t)row * CAND_CAP;
  int* ci = cand_idx_g + (size_t)row * CAND_CAP;

#define GATHER_ONE(lv, gi)                                                   \
  {                                                                          \
    const int b_ = bin_of(lv, FLO, FSC);                                     \
    if (b_ > kbin) {                                                         \
      const int p_ = atomicAdd(&kept_cnt[row], 1);                           \
      if (p_ < KEPT_CAP) { kv[p_] = lv; ki[p_] = gi; }                       \
    } else if (b_ == kbin) {                                                 \
      const int p_ = atomicAdd(&cand_cnt[row], 1);                           \
      if (p_ < CAND_CAP) { cv[p_] = lv; ci[p_] = gi; }                       \
    }                                                                        \
  }

  const int c4 = ((start & 3) == 0) ? (cnt & ~3) : 0;
  for (int i0 = tid * 4; i0 < c4; i0 += TPB_G * 4) {
    const float4 v4 = *reinterpret_cast<const float4*>(lr + start + i0);
    GATHER_ONE(v4.x, start + i0 + 0);
    GATHER_ONE(v4.y, start + i0 + 1);
    GATHER_ONE(v4.z, start + i0 + 2);
    GATHER_ONE(v4.w, start + i0 + 3);
  }
  for (int i = c4 + tid; i < cnt; i += TPB_G) {
    const float lv = lr[start + i];
    GATHER_ONE(lv, start + i);
  }
#undef GATHER_ONE
}

// ---------------- kernel 3: per-row select + sort + sample ------------------------
// mode: 0 = no ws (monolithic), 1 = ws hist only (old path), 2 = gather ran (fast)
extern "C" __global__ void __launch_bounds__(TPB_S) sampler_kernel(
    const float* __restrict__ logits, const float* __restrict__ temps,
    const void* __restrict__ topks_raw, const float* __restrict__ topps,
    const float* __restrict__ minps, const float* __restrict__ uarr,
    int* __restrict__ out, const int* __restrict__ ws_hist,
    const float* __restrict__ ws_max, const int* __restrict__ kept_cnt,
    const int* __restrict__ cand_cnt, const float* __restrict__ kept_val_g,
    const int* __restrict__ kept_idx_g, const float* __restrict__ cand_val_g,
    const int* __restrict__ cand_idx_g, int mode, int V, int B) {
  const int row = blockIdx.x;
  const int tid = threadIdx.x;

  __shared__ float cand[CAND_CAP];
  __shared__ int hist[NB];
  __shared__ int cand_idx[CAND_CAP];
  __shared__ int kept_idx[KEPT_CAP];
  __shared__ float kept_val[KEPT_CAP];
  __shared__ double sred[NW_S], sred2[NW_S];
  __shared__ int sredi[NW_S];
  __shared__ float sredf[NW_S];
  __shared__ double s_outd;
  __shared__ int s_outi;
  __shared__ float lev_lo[MAXLEV], lev_sc[MAXLEV];
  __shared__ int lev_bin[MAXLEV];
  __shared__ int s_nlev, s_bin, s_kk, s_cntbin, s_cnt, s_ccnt, s_pos;
  __shared__ float s_lmax, s_vkl, s_lo, s_sc;

  const float* lr = logits + (size_t)row * (size_t)V;
  const float T = temps[row];
  const float topp = topps[row];
  const float minp = minps[row];
  const float u = uarr[row];
  const int k = decode_k(topks_raw, row, B, V);
  const int V4 = ((V & 3) == 0) ? V : 0;
  const int haveWs = (mode >= 1) ? 1 : 0;

  int n1 = -1;
  float lmax = 0.0f;

  // ================= FAST PATH (mode 2): no row access at all =================
  if (mode == 2) {
    const int nk = kept_cnt[row];
    const int nc = cand_cnt[row];
    if (nk <= KEPT_CAP && nc <= CAND_CAP && nc >= 1) {
      for (int i = tid; i < NB; i += TPB_S) {
        int t = 0;
#pragma unroll
        for (int p = 0; p < NS; p++) t += ws_hist[(size_t)(row * NS + p) * NB + i];
        hist[i] = t;
      }
      if (tid == 0) {
        float m = ws_max[row * NS];
#pragma unroll
        for (int p = 1; p < NS; p++) m = fmaxf(m, ws_max[row * NS + p]);
        s_lmax = m;
      }
      __syncthreads();
      locate_kbin(hist, k, &s_bin, &s_kk, &s_cntbin);
      __syncthreads();
      // load candidates into LDS
      for (int t = tid; t < nc; t += TPB_S) {
        cand[t] = cand_val_g[(size_t)row * CAND_CAP + t];
        cand_idx[t] = cand_idx_g[(size_t)row * CAND_CAP + t];
      }
      __syncthreads();
      // tie-aware rank select of v_k among candidates
      {
        int kkq = s_kk;
        if (kkq > nc) kkq = nc;
        for (int t = tid; t < nc; t += TPB_S) {
          const float v = cand[t];
          int rank = 0;
          for (int j = 0; j < nc; j++) {
            const float cj = cand[j];
            rank += (cj > v) ? 1 : ((cj == v && j < t) ? 1 : 0);
          }
          if (rank == kkq - 1) s_vkl = v;   // exactly one thread matches
        }
      }
      __syncthreads();
      const float vkl = s_vkl;
      // load kept set, then append candidates >= v_k
      for (int t = tid; t < nk; t += TPB_S) {
        kept_val[t] = kept_val_g[(size_t)row * KEPT_CAP + t];
        kept_idx[t] = kept_idx_g[(size_t)row * KEPT_CAP + t];
      }
      if (tid == 0) s_cnt = nk;
      __syncthreads();
      for (int t = tid; t < nc; t += TPB_S) {
        const float v = cand[t];
        if (v >= vkl) {
          const int p = atomicAdd(&s_cnt, 1);
          if (p < KEPT_CAP) { kept_val[p] = v; kept_idx[p] = cand_idx[t]; }
        }
      }
      __syncthreads();
      n1 = (s_cnt < KEPT_CAP) ? s_cnt : KEPT_CAP;
      lmax = s_lmax;
    }
  }

  // ================= FALLBACK PATH (verified round-4 stages A–D) ==============
  if (n1 < 0) {
    // ---------- stage A: row max + fixed-bound histogram ----------
    if (haveWs) {
      for (int i = tid; i < NB; i += TPB_S) {
        int t = 0;
#pragma unroll
        for (int p = 0; p < NS; p++) t += ws_hist[(size_t)(row * NS + p) * NB + i];
        hist[i] = t;
      }
      if (tid == 0) {
        float m = ws_max[row * NS];
#pragma unroll
        for (int p = 1; p < NS; p++) m = fmaxf(m, ws_max[row * NS + p]);
        s_lmax = m;
      }
      __syncthreads();
    } else {
      for (int i = tid; i < NB; i += TPB_S) hist[i] = 0;
      __syncthreads();
      float mx = -FLT_MAX;
      ROW_LOOP(mx = fmaxf(mx, lv); atomicAdd(&hist[bin_of(lv, FLO, FSC)], 1););
      mx = wmax_f(mx);
      __syncthreads();
      if ((tid & 63) == 0) sredf[tid >> 6] = mx;
      __syncthreads();
      if (tid == 0) {
        float t = sredf[0];
        for (int i = 1; i < NW_S; i++) t = fmaxf(t, sredf[i]);
        s_lmax = t;
      }
      __syncthreads();
    }
    lmax = s_lmax;

    // ---------- stage B: locate bin of the k-th largest (refinement fallback) --
    if (tid == 0) {
      s_kk = k; s_nlev = 0; s_vkl = lmax; s_lo = FLO; s_sc = FSC;
    }
    __syncthreads();

    for (int lev = 0; lev < MAXLEV; lev++) {
      if (tid < 64) {
        const int l = tid;
        const int b0 = NB - (l + 1) * (NB / 64);
        int c = 0;
#pragma unroll
        for (int j = 0; j < NB / 64; j++) c += hist[b0 + j];
        int incl = c;
#pragma unroll
        for (int o = 1; o < 64; o <<= 1) {
          int t2 = __shfl_up(incl, o);
          if (l >= o) incl += t2;
        }
        const int pref = incl - c;
        const int kk = s_kk;
        if (pref < kk && kk <= pref + c) {
          int rem = kk - pref;
          for (int j = NB / 64 - 1; j >= 0; j--) {
            const int h = hist[b0 + j];
            if (rem <= h) { s_bin = b0 + j; s_cntbin = h; s_kk = rem; break; }
            rem -= h;
          }
        }
      }
      __syncthreads();
      if (tid == 0) {
        lev_lo[lev] = s_lo; lev_sc[lev] = s_sc; lev_bin[lev] = s_bin;
        s_nlev = lev + 1;
      }
      __syncthreads();
      if (s_cntbin <= CAND_CAP) break;
      const float nlo = s_lo + (float)s_bin / s_sc;
      const float nsc = s_sc * (float)NB;
      const bool degw = !((nlo + (float)NB / nsc) > nlo);
      if (lev + 1 >= MAXLEV || degw) break;
      __syncthreads();
      if (tid == 0) { s_lo = nlo; s_sc = nsc; }
      for (int i = tid; i < NB; i += TPB_S) hist[i] = 0;
      __syncthreads();
      const int nl = lev + 1;
      ROW_LOOP(
        bool memb = true;
        for (int L = 0; L < nl; L++) {
          if (bin_of(lv, lev_lo[L], lev_sc[L]) != lev_bin[L]) { memb = false; break; }
        }
        if (memb) atomicAdd(&hist[bin_of(lv, nlo, nsc)], 1););
      __syncthreads();
    }

    // ---------- stage C: fused gather (kept-direct + candidates) ----------
    if (tid == 0) { s_cnt = 0; s_ccnt = 0; }
    __syncthreads();
    {
      const int nl = s_nlev;
      ROW_LOOP(
        int cls = 2;
        for (int L = 0; L < nl; L++) {
          const int b = bin_of(lv, lev_lo[L], lev_sc[L]);
          if (b > lev_bin[L]) { cls = 1; break; }
          if (b < lev_bin[L]) { cls = 0; break; }
        }
        if (cls == 1) {
          int p = atomicAdd(&s_cnt, 1);
          if (p < KEPT_CAP) { kept_idx[p] = gi; kept_val[p] = lv; }
        } else if (cls == 2) {
          int p = atomicAdd(&s_ccnt, 1);
          if (p < CAND_CAP) { cand[p] = lv; cand_idx[p] = gi; }
        });
    }
    __syncthreads();

    // ---------- stage D: tie-aware rank select + append ----------
    {
      const int n = (s_ccnt < CAND_CAP) ? s_ccnt : CAND_CAP;
      int kkq = s_kk;
      if (kkq > n) kkq = n;
      for (int t = tid; t < n; t += TPB_S) {
        const float v = cand[t];
        int rank = 0;
        for (int j = 0; j < n; j++) {
          const float cj = cand[j];
          rank += (cj > v) ? 1 : ((cj == v && j < t) ? 1 : 0);
        }
        if (rank == kkq - 1) s_vkl = v;
      }
    }
    __syncthreads();
    const float vkl = s_vkl;
    {
      const int n = (s_ccnt < CAND_CAP) ? s_ccnt : CAND_CAP;
      for (int t = tid; t < n; t += TPB_S) {
        const float v = cand[t];
        if (v >= vkl) {
          int p = atomicAdd(&s_cnt, 1);
          if (p < KEPT_CAP) { kept_idx[p] = cand_idx[t]; kept_val[p] = v; }
        }
      }
    }
    __syncthreads();
    n1 = (s_cnt < KEPT_CAP) ? s_cnt : KEPT_CAP;
  }

  if (n1 <= 0) {  // unreachable with valid data
    if (tid == 0) out[row] = 0;
    return;
  }

  // ---------- logits -> probs (precise exp only for kept) ----------
  const float xmaxT = lmax / T;  // == max_i fl(l_i/T) (division by T>0 is monotone)
  double lsum = 0.0;
  for (int t = tid; t < n1; t += TPB_S) {
    const float x = kept_val[t] / T;
    const float w = expf(x - xmaxT);
    kept_val[t] = w;
    lsum += (double)w;
  }
  const float s1f = (float)blk_sum_d(lsum, sred, &s_outd);
  for (int t = tid; t < n1; t += TPB_S) kept_val[t] = kept_val[t] / s1f;

  // pad & bitonic sort descending by value (idx carried)
  int M = 1;
  while (M < n1) M <<= 1;
  if (M < 2) M = 2;
  __syncthreads();
  for (int t = n1 + tid; t < M; t += TPB_S) { kept_val[t] = -1.0f; kept_idx[t] = 0x7FFFFFFF; }
  __syncthreads();
  for (int len = 2; len <= M; len <<= 1) {
    for (int str = len >> 1; str > 0; str >>= 1) {
      for (int t = tid; t < (M >> 1); t += TPB_S) {
        const int i = ((t & ~(str - 1)) << 1) | (t & (str - 1));
        const int j2 = i | str;
        const float vi = kept_val[i], vj = kept_val[j2];
        const bool descSeg = ((i & len) == 0);
        if (descSeg ? (vi < vj) : (vi > vj)) {
          kept_val[i] = vj; kept_val[j2] = vi;
          const int ti = kept_idx[i];
          kept_idx[i] = kept_idx[j2]; kept_idx[j2] = ti;
        }
      }
      __syncthreads();
    }
  }

  // ---------- top-p: (excl cum < p) keeps a prefix; then >= p_thresh ----------
  const int C = (M + TPB_S - 1) / TPB_S;
  double cls0 = 0.0;
  for (int j = 0; j < C; j++) {
    const int p = tid * C + j;
    if (p < n1) cls0 += (double)kept_val[p];
  }
  const double excl0 = blk_exscan_d(cls0, sred, sred2);
  int lc = 0;
  {
    double run = excl0;
    for (int j = 0; j < C; j++) {
      const int p = tid * C + j;
      if (p < n1) {
        if (run < (double)topp) lc++;
        run += (double)kept_val[p];
      }
    }
  }
  const int cnt = blk_sum_i(lc, sredi, &s_outi);  // >= 1 always
  const float pthr = kept_val[cnt - 1];

  int ln2 = 0;
  double ls2 = 0.0;
  for (int j = 0; j < C; j++) {
    const int p = tid * C + j;
    if (p < n1) {
      const float v = kept_val[p];
      if (v >= pthr) { ln2++; ls2 += (double)v; }
    }
  }
  const int n2 = blk_sum_i(ln2, sredi, &s_outi);
  const float s2f = (float)blk_sum_d(ls2, sred, &s_outd);

  // ---------- min-p (survivors are a prefix in sorted order) ----------
  const float maxr = kept_val[0] / s2f;
  const float th4 = minp * maxr;
  int ln3 = 0;
  double ls3 = 0.0;
  for (int j = 0; j < C; j++) {
    const int p = tid * C + j;
    if (p < n2) {
      const float r = kept_val[p] / s2f;
      if (r >= th4) { ln3++; ls3 += (double)r; }
    }
  }
  const int n3 = blk_sum_i(ln3, sredi, &s_outi);
  const float s3f = (float)blk_sum_d(ls3, sred, &s_outd);

  // ---------- finalize probs, sort survivors by index, inverse-CDF ----------
  int M3 = 1;
  while (M3 < n3) M3 <<= 1;
  if (M3 < 2) M3 = 2;
  __syncthreads();
  for (int t = tid; t < M3; t += TPB_S) {
    if (t < n3) {
      const float r = kept_val[t] / s2f;
      kept_val[t] = r / s3f;
    } else {
      kept_val[t] = 0.0f;
      kept_idx[t] = 0x7FFFFFFF;
    }
  }
  __syncthreads();
  for (int len = 2; len <= M3; len <<= 1) {
    for (int str = len >> 1; str > 0; str >>= 1) {
      for (int t = tid; t < (M3 >> 1); t += TPB_S) {
        const int i = ((t & ~(str - 1)) << 1) | (t & (str - 1));
        const int j2 = i | str;
        const int ki = kept_idx[i], kj = kept_idx[j2];
        const bool ascSeg = ((i & len) == 0);
        if (ascSeg ? (ki > kj) : (ki < kj)) {
          kept_idx[i] = kj; kept_idx[j2] = ki;
          const float tv = kept_val[i];
          kept_val[i] = kept_val[j2]; kept_val[j2] = tv;
        }
      }
      __syncthreads();
    }
  }
  const int C3 = (M3 + TPB_S - 1) / TPB_S;
  double cls3 = 0.0;
  for (int j = 0; j < C3; j++) {
    const int p = tid * C3 + j;
    if (p < n3) cls3 += (double)kept_val[p];
  }
  const double e5 = blk_exscan_d(cls3, sred, sred2);
  if (tid == 0) s_pos = 0x7FFFFFFF;
  __syncthreads();
  {
    double run = e5;
    int found = -1;
    for (int j = 0; j < C3; j++) {
      const int p = tid * C3 + j;
      if (p < n3) {
        run += (double)kept_val[p];
        if (run >= (double)u) { found = p; break; }
      }
    }
    if (found >= 0) atomicMin(&s_pos, found);
  }
  __syncthreads();
  if (tid == 0) {
    int token;
    if (!(u > 0.0f)) token = 0;                   // all cdf >= 0 == u -> count 0
    else if (s_pos == 0x7FFFFFFF) token = V - 1;  // u beyond total mass -> clip
    else token = kept_idx[s_pos];                 // == count of cdf entries < u
    out[row] = token;
  }
}

extern "C" void kernel_launch(void* const* d_in, const int* in_sizes, int n_in,
                              void* d_out, int out_size, void* d_ws, size_t ws_size,
                              hipStream_t stream) {
  const float* logits = (const float*)d_in[0];
  const float* temps = (const float*)d_in[1];
  const void* topks = d_in[2];
  const float* topps = (const float*)d_in[3];
  const float* minps = (const float*)d_in[4];
  const float* u = (const float*)d_in[5];
  int* out = (int*)d_out;
  const int B = in_sizes[1];
  const int V = in_sizes[0] / B;
  (void)n_in; (void)out_size;

  // ws layout
  char* p = (char*)d_ws;
  int* ws_hist = (int*)p;        p += (size_t)NS * B * NB * sizeof(int);
  float* ws_max = (float*)p;     p += (size_t)NS * B * sizeof(float);
  int* kept_cnt = (int*)p;       p += (size_t)B * sizeof(int);
  int* cand_cnt = (int*)p;       p += (size_t)B * sizeof(int);
  float* kept_val_g = (float*)p; p += (size_t)B * KEPT_CAP * sizeof(float);
  int* kept_idx_g = (int*)p;     p += (size_t)B * KEPT_CAP * sizeof(int);
  float* cand_val_g = (float*)p; p += (size_t)B * CAND_CAP * sizeof(float);
  int* cand_idx_g = (int*)p;     p += (size_t)B * CAND_CAP * sizeof(int);
  const size_t need_full = (size_t)(p - (char*)d_ws);
  const size_t need_hist = (size_t)NS * B * NB * sizeof(int) + (size_t)NS * B * sizeof(float);

  int mode = 0;
  if (d_ws && ws_size >= need_full) mode = 2;
  else if (d_ws && ws_size >= need_hist) mode = 1;

  if (mode >= 1) {
    hist_max_kernel<<<dim3(B * NS), dim3(TPB_H), 0, stream>>>(
        logits, V, ws_hist, ws_max, kept_cnt, cand_cnt, (mode == 2) ? 1 : 0);
  }
  if (mode == 2) {
    gather_kernel<<<dim3(B * NS), dim3(TPB_G), 0, stream>>>(
        logits, topks, V, B, ws_hist, kept_cnt, cand_cnt,
        kept_val_g, kept_idx_g, cand_val_g, cand_idx_g);
  }
  sampler_kernel<<<dim3(B), dim3(TPB_S), 0, stream>>>(
      logits, temps, topks, topps, minps, u, out, ws_hist, ws_max,
      kept_cnt, cand_cnt, kept_val_g, kept_idx_g, cand_val_g, cand_idx_g,
      mode, V, B);
}

// Round 10
// 200.850 us; speedup vs baseline: 2.0945x; 2.0945x over previous
//
#include <hip/hip_runtime.h>
#include <float.h>
#include <stdint.h>

#define TPB_H 1024              // histogram kernel block
#define TPB_G 1024              // gather kernel block
#define TPB_S 512               // sampler kernel block (8 waves)
#define NB 2048
#define NS 4                    // row-parts for hist/gather kernels (4*128 = 512 blocks)
#define CAND_CAP 2048
#define KEPT_CAP 4096
#define MAXLEV 6
#define NW_H (TPB_H / 64)
#define NW_S (TPB_S / 64)
#define FLO (-16.0f)
#define FSC ((float)NB / 32.0f)  // 64 bins per unit over [-16,16)

// Monotone, clamped linear binning — must be bit-identical across all passes.
__device__ __forceinline__ int bin_of(float x, float lo, float sc) {
  float bf = (x - lo) * sc;
  if (!(bf > 0.0f)) return 0;                 // also catches NaN
  if (bf >= (float)(NB - 1)) return NB - 1;
  return (int)bf;
}

__device__ __forceinline__ double wsum_d(double v) {
#pragma unroll
  for (int o = 32; o > 0; o >>= 1) v += __shfl_xor(v, o);
  return v;
}
__device__ __forceinline__ int wsum_i(int v) {
#pragma unroll
  for (int o = 32; o > 0; o >>= 1) v += __shfl_xor(v, o);
  return v;
}
__device__ __forceinline__ float wmax_f(float v) {
#pragma unroll
  for (int o = 32; o > 0; o >>= 1) v = fmaxf(v, __shfl_xor(v, o));
  return v;
}

// Wave-aggregated LDS counter push: 1 LDS atomic per wave-site instead of
// per-lane. Returns slot index for active lanes (-1 site-wide if none active).
// Must be called convergently by the lanes currently executing.
__device__ __forceinline__ int wave_push(int* cnt_lds, bool active) {
  const unsigned long long mask = __ballot(active);
  if (mask == 0ull) return -1;
  const int lane = (int)(threadIdx.x & 63);
  const unsigned long long lanebit = 1ull << lane;
  const int prefix = __popcll(mask & (lanebit - 1ull));
  const int leader = (int)(__ffsll((unsigned long long)mask) - 1);
  int base = 0;
  if (active && prefix == 0) base = atomicAdd(cnt_lds, __popcll(mask));
  base = __shfl(base, leader);
  return base + prefix;
}

// ---- sampler-block (TPB_S) reductions/scans ----
__device__ __forceinline__ double blk_sum_d(double v, double* sred, double* out) {
  v = wsum_d(v);
  __syncthreads();
  if ((threadIdx.x & 63) == 0) sred[threadIdx.x >> 6] = v;
  __syncthreads();
  if (threadIdx.x == 0) {
    double t = 0.0;
#pragma unroll
    for (int i = 0; i < NW_S; i++) t += sred[i];
    *out = t;
  }
  __syncthreads();
  return *out;
}

__device__ __forceinline__ int blk_sum_i(int v, int* sredi, int* out) {
  v = wsum_i(v);
  __syncthreads();
  if ((threadIdx.x & 63) == 0) sredi[threadIdx.x >> 6] = v;
  __syncthreads();
  if (threadIdx.x == 0) {
    int t = 0;
#pragma unroll
    for (int i = 0; i < NW_S; i++) t += sredi[i];
    *out = t;
  }
  __syncthreads();
  return *out;
}

// exclusive f64 block prefix: wave shuffle-scan + 8-entry aggregate scan (3 barriers)
__device__ __forceinline__ double blk_exscan_d(double v, double* sw, double* sw2) {
  const int tid = threadIdx.x;
  const int lane = tid & 63, wid = tid >> 6;
  __syncthreads();          // protect sw/sw2 reuse against preceding readers
  double incl = v;
#pragma unroll
  for (int o = 1; o < 64; o <<= 1) {
    double t = __shfl_up(incl, o);
    if (lane >= o) incl += t;
  }
  if (lane == 63) sw[wid] = incl;
  __syncthreads();
  if (tid == 0) {
    double acc = 0.0;
#pragma unroll
    for (int i = 0; i < NW_S; i++) { double t = sw[i]; sw2[i] = acc; acc += t; }
  }
  __syncthreads();
  return sw2[wid] + (incl - v);
}

// ======================= sorting machinery (sampler) =========================
// Hybrid bitonic: strides <128 run wave-local in registers (2 elems/lane,
// shfl_xor exchange, no barriers); strides >=128 run in LDS with barriers.
// Every exchange's keep-decision is symmetric across the lane pair (desc
// derived from the pair's LOWER element index), so the array always remains a
// permutation — worst case mis-ordered, never corrupted. A sortedness check
// falls back to the verified full LDS bitonic.

// value sort: float key DESC, int payload
__device__ __forceinline__ void xchg_f(float& k, int& p, int e, int s, int len) {
  const float ok = __shfl_xor(k, s);
  const int op = __shfl_xor(p, s);
  const bool lower = ((e & s) == 0);
  const bool desc = (((e & ~s) & len) == 0);   // identical on both pair lanes
  const bool keep = desc ? (lower ? (k >= ok) : (k <= ok))
                         : (lower ? (k <= ok) : (k >= ok));
  if (!keep) { k = ok; p = op; }
}

// index sort: int key ASC, float payload
__device__ __forceinline__ void xchg_i(int& k, float& p, int e, int s, int len) {
  const int ok = __shfl_xor(k, s);
  const float op = __shfl_xor(p, s);
  const bool lower = ((e & s) == 0);
  const bool asc = (((e & ~s) & len) == 0);
  const bool keep = asc ? (lower ? (k <= ok) : (k >= ok))
                        : (lower ? (k >= ok) : (k <= ok));
  if (!keep) { k = ok; p = op; }
}

__device__ __forceinline__ void reg_sort128_f(float& ka, int& pa, float& kb, int& pb,
                                              int base, int lane) {
  const int ea = base + lane, eb = base + 64 + lane;
  for (int len = 2; len <= 128; len <<= 1) {
    if (len == 128) {
      const bool d = ((base & 128) == 0);
      if (d ? (ka < kb) : (ka > kb)) {
        float tk = ka; ka = kb; kb = tk; int tp = pa; pa = pb; pb = tp;
      }
      for (int s = 32; s >= 1; s >>= 1) { xchg_f(ka, pa, ea, s, len); xchg_f(kb, pb, eb, s, len); }
    } else {
      for (int s = len >> 1; s >= 1; s >>= 1) { xchg_f(ka, pa, ea, s, len); xchg_f(kb, pb, eb, s, len); }
    }
  }
}

__device__ __forceinline__ void reg_merge128_f(float& ka, int& pa, float& kb, int& pb,
                                               int base, int lane, int len) {
  const int ea = base + lane, eb = base + 64 + lane;
  const bool d = ((base & len) == 0);
  if (d ? (ka < kb) : (ka > kb)) {
    float tk = ka; ka = kb; kb = tk; int tp = pa; pa = pb; pb = tp;
  }
  for (int s = 32; s >= 1; s >>= 1) { xchg_f(ka, pa, ea, s, len); xchg_f(kb, pb, eb, s, len); }
}

__device__ __forceinline__ void reg_sort128_i(int& ka, float& pa, int& kb, float& pb,
                                              int base, int lane) {
  const int ea = base + lane, eb = base + 64 + lane;
  for (int len = 2; len <= 128; len <<= 1) {
    if (len == 128) {
      const bool a = ((base & 128) == 0);
      if (a ? (ka > kb) : (ka < kb)) {
        int tk = ka; ka = kb; kb = tk; float tp = pa; pa = pb; pb = tp;
      }
      for (int s = 32; s >= 1; s >>= 1) { xchg_i(ka, pa, ea, s, len); xchg_i(kb, pb, eb, s, len); }
    } else {
      for (int s = len >> 1; s >= 1; s >>= 1) { xchg_i(ka, pa, ea, s, len); xchg_i(kb, pb, eb, s, len); }
    }
  }
}

__device__ __forceinline__ void reg_merge128_i(int& ka, float& pa, int& kb, float& pb,
                                               int base, int lane, int len) {
  const int ea = base + lane, eb = base + 64 + lane;
  const bool a = ((base & len) == 0);
  if (a ? (ka > kb) : (ka < kb)) {
    int tk = ka; ka = kb; kb = tk; float tp = pa; pa = pb; pb = tp;
  }
  for (int s = 32; s >= 1; s >>= 1) { xchg_i(ka, pa, ea, s, len); xchg_i(kb, pb, eb, s, len); }
}

// fallback: full LDS bitonic (verified round-4 code, works on any permutation)
__device__ void bitonic_desc_f(float* key, int* pay, int M) {
  const int tid = threadIdx.x;
  for (int len = 2; len <= M; len <<= 1) {
    for (int str = len >> 1; str > 0; str >>= 1) {
      for (int t = tid; t < (M >> 1); t += TPB_S) {
        const int i = ((t & ~(str - 1)) << 1) | (t & (str - 1));
        const int j2 = i | str;
        const float vi = key[i], vj = key[j2];
        const bool descSeg = ((i & len) == 0);
        if (descSeg ? (vi < vj) : (vi > vj)) {
          key[i] = vj; key[j2] = vi;
          const int ti = pay[i]; pay[i] = pay[j2]; pay[j2] = ti;
        }
      }
      __syncthreads();
    }
  }
}

__device__ void bitonic_asc_i(int* key, float* pay, int M) {
  const int tid = threadIdx.x;
  for (int len = 2; len <= M; len <<= 1) {
    for (int str = len >> 1; str > 0; str >>= 1) {
      for (int t = tid; t < (M >> 1); t += TPB_S) {
        const int i = ((t & ~(str - 1)) << 1) | (t & (str - 1));
        const int j2 = i | str;
        const int ki = key[i], kj = key[j2];
        const bool ascSeg = ((i & len) == 0);
        if (ascSeg ? (ki > kj) : (ki < kj)) {
          key[i] = kj; key[j2] = ki;
          const float tv = pay[i]; pay[i] = pay[j2]; pay[j2] = tv;
        }
      }
      __syncthreads();
    }
  }
}

// hybrid sorts; M must be a power of two >= 128
__device__ void hybrid_sort_desc_f(float* key, int* pay, int M) {
  const int tid = threadIdx.x;
  const int wid = tid >> 6, lane = tid & 63;
  const int nblk = M >> 7;
  __syncthreads();
  for (int blk = wid; blk < nblk; blk += NW_S) {
    const int base = blk << 7;
    float ka = key[base + lane]; int pa = pay[base + lane];
    float kb = key[base + 64 + lane]; int pb = pay[base + 64 + lane];
    reg_sort128_f(ka, pa, kb, pb, base, lane);
    key[base + lane] = ka; pay[base + lane] = pa;
    key[base + 64 + lane] = kb; pay[base + 64 + lane] = pb;
  }
  __syncthreads();
  for (int len = 256; len <= M; len <<= 1) {
    for (int str = len >> 1; str >= 128; str >>= 1) {
      for (int t = tid; t < (M >> 1); t += TPB_S) {
        const int i = ((t & ~(str - 1)) << 1) | (t & (str - 1));
        const int j2 = i | str;
        const float vi = key[i], vj = key[j2];
        const bool d = ((i & len) == 0);
        if (d ? (vi < vj) : (vi > vj)) {
          key[i] = vj; key[j2] = vi;
          const int ti = pay[i]; pay[i] = pay[j2]; pay[j2] = ti;
        }
      }
      __syncthreads();
    }
    for (int blk = wid; blk < nblk; blk += NW_S) {
      const int base = blk << 7;
      float ka = key[base + lane]; int pa = pay[base + lane];
      float kb = key[base + 64 + lane]; int pb = pay[base + 64 + lane];
      reg_merge128_f(ka, pa, kb, pb, base, lane, len);
      key[base + lane] = ka; pay[base + lane] = pa;
      key[base + 64 + lane] = kb; pay[base + 64 + lane] = pb;
    }
    __syncthreads();
  }
}

__device__ void hybrid_sort_asc_i(int* key, float* pay, int M) {
  const int tid = threadIdx.x;
  const int wid = tid >> 6, lane = tid & 63;
  const int nblk = M >> 7;
  __syncthreads();
  for (int blk = wid; blk < nblk; blk += NW_S) {
    const int base = blk << 7;
    int ka = key[base + lane]; float pa = pay[base + lane];
    int kb = key[base + 64 + lane]; float pb = pay[base + 64 + lane];
    reg_sort128_i(ka, pa, kb, pb, base, lane);
    key[base + lane] = ka; pay[base + lane] = pa;
    key[base + 64 + lane] = kb; pay[base + 64 + lane] = pb;
  }
  __syncthreads();
  for (int len = 256; len <= M; len <<= 1) {
    for (int str = len >> 1; str >= 128; str >>= 1) {
      for (int t = tid; t < (M >> 1); t += TPB_S) {
        const int i = ((t & ~(str - 1)) << 1) | (t & (str - 1));
        const int j2 = i | str;
        const int ki = key[i], kj = key[j2];
        const bool a = ((i & len) == 0);
        if (a ? (ki > kj) : (ki < kj)) {
          key[i] = kj; key[j2] = ki;
          const float tv = pay[i]; pay[i] = pay[j2]; pay[j2] = tv;
        }
      }
      __syncthreads();
    }
    for (int blk = wid; blk < nblk; blk += NW_S) {
      const int base = blk << 7;
      int ka = key[base + lane]; float pa = pay[base + lane];
      int kb = key[base + 64 + lane]; float pb = pay[base + 64 + lane];
      reg_merge128_i(ka, pa, kb, pb, base, lane, len);
      key[base + lane] = ka; pay[base + lane] = pa;
      key[base + 64 + lane] = kb; pay[base + 64 + lane] = pb;
    }
    __syncthreads();
  }
}

// wave 0: given merged hist[NB] (desc scan from top) and rank k, find the bin
// holding the k-th largest, its count, and the within-bin rank kk (from top).
__device__ __forceinline__ void locate_kbin(const int* hist, int k,
                                            int* s_bin, int* s_kk, int* s_cntbin) {
  if (threadIdx.x < 64) {
    const int l = threadIdx.x;
    const int b0 = NB - (l + 1) * (NB / 64);   // lane 0 covers highest bins
    int c = 0;
#pragma unroll
    for (int j = 0; j < NB / 64; j++) c += hist[b0 + j];
    int incl = c;
#pragma unroll
    for (int o = 1; o < 64; o <<= 1) {
      int t2 = __shfl_up(incl, o);
      if (l >= o) incl += t2;
    }
    const int pref = incl - c;  // count in strictly-higher chunks
    if (pref < k && k <= pref + c) {
      int rem = k - pref;
      for (int j = NB / 64 - 1; j >= 0; j--) {
        const int h = hist[b0 + j];
        if (rem <= h) { *s_bin = b0 + j; *s_cntbin = h; *s_kk = rem; break; }
        rem -= h;
      }
    }
  }
}

// decode top_ks[row]: reference dtype int64, but harness may hand int32.
__device__ __forceinline__ int decode_k(const void* topks_raw, int row, int B, int V) {
  const int* ip = (const int*)topks_raw;
  const bool is64 = (B < 2) || (ip[1] == 0);
  long long kraw = is64 ? ((const long long*)topks_raw)[row] : (long long)ip[row];
  long long kidx = kraw - 1;
  if (kidx < 0) kidx = 0;
  if (kidx > (long long)(V - 1)) kidx = (long long)(V - 1);
  return (int)kidx + 1;
}

// Iterate a row; lv = raw logit, gi = global index. V4 is the vec4-covered prefix.
#define ROW_LOOP(...)                                                                  \
  do {                                                                                 \
    for (int i0_ = tid * 4; i0_ < V4; i0_ += TPB_S * 4) {                              \
      const float4 v4_ = *reinterpret_cast<const float4*>(lr + i0_);                   \
      { const float lv = v4_.x; const int gi = i0_ + 0; (void)gi; __VA_ARGS__ }        \
      { const float lv = v4_.y; const int gi = i0_ + 1; (void)gi; __VA_ARGS__ }        \
      { const float lv = v4_.z; const int gi = i0_ + 2; (void)gi; __VA_ARGS__ }        \
      { const float lv = v4_.w; const int gi = i0_ + 3; (void)gi; __VA_ARGS__ }        \
    }                                                                                  \
    for (int gi = V4 + tid; gi < V; gi += TPB_S) {                                     \
      const float lv = lr[gi]; (void)gi; __VA_ARGS__                                   \
    }                                                                                  \
  } while (0)

// ---------------- kernel 1: per (row, part) fixed-bin histogram + partial max ----
extern "C" __global__ void __launch_bounds__(TPB_H) hist_max_kernel(
    const float* __restrict__ logits, int V,
    int* __restrict__ ws_hist, float* __restrict__ ws_max,
    int* __restrict__ kept_cnt, int* __restrict__ cand_cnt, int zeroCnts) {
  __shared__ int hist[NB];
  __shared__ float sredf[NW_H];
  const int tid = threadIdx.x;
  const int row = blockIdx.x / NS;
  const int part = blockIdx.x % NS;
  const float* lr = logits + (size_t)row * (size_t)V;
  const int start = (int)(((long long)V * part) / NS);
  const int end = (int)(((long long)V * (part + 1)) / NS);
  const int cnt = end - start;

  if (zeroCnts && part == 0 && tid == 0) { kept_cnt[row] = 0; cand_cnt[row] = 0; }

  for (int i = tid; i < NB; i += TPB_H) hist[i] = 0;
  __syncthreads();

  float mx = -FLT_MAX;
  const int c4 = ((start & 3) == 0) ? (cnt & ~3) : 0;
  for (int i0 = tid * 4; i0 < c4; i0 += TPB_H * 4) {
    const float4 v4 = *reinterpret_cast<const float4*>(lr + start + i0);
    mx = fmaxf(mx, v4.x); atomicAdd(&hist[bin_of(v4.x, FLO, FSC)], 1);
    mx = fmaxf(mx, v4.y); atomicAdd(&hist[bin_of(v4.y, FLO, FSC)], 1);
    mx = fmaxf(mx, v4.z); atomicAdd(&hist[bin_of(v4.z, FLO, FSC)], 1);
    mx = fmaxf(mx, v4.w); atomicAdd(&hist[bin_of(v4.w, FLO, FSC)], 1);
  }
  for (int i = c4 + tid; i < cnt; i += TPB_H) {
    const float lv = lr[start + i];
    mx = fmaxf(mx, lv); atomicAdd(&hist[bin_of(lv, FLO, FSC)], 1);
  }

  mx = wmax_f(mx);
  __syncthreads();
  if ((tid & 63) == 0) sredf[tid >> 6] = mx;
  __syncthreads();
  if (tid == 0) {
    float t = sredf[0];
    for (int i = 1; i < NW_H; i++) t = fmaxf(t, sredf[i]);
    ws_max[blockIdx.x] = t;
  }
  __syncthreads();
  int* dst = ws_hist + (size_t)blockIdx.x * NB;
  for (int i = tid; i < NB; i += TPB_H) dst[i] = hist[i];
}

// ---------------- kernel 2: per (row, part) gather, LDS-staged ------------------
// Classify into LDS buffers (wave-aggregated LDS counter pushes), then reserve a
// contiguous global range with ONE atomic per counter per block (8/row total),
// then coalesced copy-out. Global counters hold TRUE counts (overflow -> sampler
// falls back), staged writes are clamped to caps.
extern "C" __global__ void __launch_bounds__(TPB_G) gather_kernel(
    const float* __restrict__ logits, const void* __restrict__ topks_raw,
    int V, int B, const int* __restrict__ ws_hist,
    int* __restrict__ kept_cnt, int* __restrict__ cand_cnt,
    float* __restrict__ kept_val_g, int* __restrict__ kept_idx_g,
    float* __restrict__ cand_val_g, int* __restrict__ cand_idx_g) {
  __shared__ int hist[NB];
  __shared__ float lkv[KEPT_CAP];
  __shared__ int lki[KEPT_CAP];
  __shared__ float lcv[CAND_CAP];
  __shared__ int lci[CAND_CAP];
  __shared__ int s_bin, s_kk, s_cntbin, l_kc, l_cc, s_gk, s_gc;
  const int tid = threadIdx.x;
  const int row = blockIdx.x / NS;
  const int part = blockIdx.x % NS;
  const int k = decode_k(topks_raw, row, B, V);

  // merge the NS part-histograms for this row (redundant per part-block, cheap)
  for (int i = tid; i < NB; i += TPB_G) {
    int t = 0;
#pragma unroll
    for (int p = 0; p < NS; p++) t += ws_hist[(size_t)(row * NS + p) * NB + i];
    hist[i] = t;
  }
  if (tid == 0) { l_kc = 0; l_cc = 0; }
  __syncthreads();
  locate_kbin(hist, k, &s_bin, &s_kk, &s_cntbin);
  __syncthreads();
  const int kbin = s_bin;

  const float* lr = logits + (size_t)row * (size_t)V;
  const int start = (int)(((long long)V * part) / NS);
  const int end = (int)(((long long)V * (part + 1)) / NS);
  const int cnt = end - start;

#define GATHER_ONE(lv, gi)                                                   \
  {                                                                          \
    const int b_ = bin_of(lv, FLO, FSC);                                     \
    const bool isk_ = (b_ > kbin);                                           \
    const bool isc_ = (b_ == kbin);                                          \
    const int pk_ = wave_push(&l_kc, isk_);                                  \
    if (isk_ && pk_ < KEPT_CAP) { lkv[pk_] = lv; lki[pk_] = gi; }            \
    const int pc_ = wave_push(&l_cc, isc_);                                  \
    if (isc_ && pc_ < CAND_CAP) { lcv[pc_] = lv; lci[pc_] = gi; }            \
  }

  const int c4 = ((start & 3) == 0) ? (cnt & ~3) : 0;
  for (int i0 = tid * 4; i0 < c4; i0 += TPB_G * 4) {
    const float4 v4 = *reinterpret_cast<const float4*>(lr + start + i0);
    GATHER_ONE(v4.x, start + i0 + 0);
    GATHER_ONE(v4.y, start + i0 + 1);
    GATHER_ONE(v4.z, start + i0 + 2);
    GATHER_ONE(v4.w, start + i0 + 3);
  }
  for (int i = c4 + tid; i < cnt; i += TPB_G) {
    const float lv = lr[start + i];
    GATHER_ONE(lv, start + i);
  }
#undef GATHER_ONE

  __syncthreads();
  if (tid == 0) {
    s_gk = atomicAdd(&kept_cnt[row], l_kc);   // reserve ranges; true counts
    s_gc = atomicAdd(&cand_cnt[row], l_cc);
  }
  __syncthreads();
  {
    float* kv = kept_val_g + (size_t)row * KEPT_CAP;
    int* ki = kept_idx_g + (size_t)row * KEPT_CAP;
    float* cv = cand_val_g + (size_t)row * CAND_CAP;
    int* ci = cand_idx_g + (size_t)row * CAND_CAP;
    const int nks = (l_kc < KEPT_CAP) ? l_kc : KEPT_CAP;   // staged entries
    const int ncs = (l_cc < CAND_CAP) ? l_cc : CAND_CAP;
    for (int t = tid; t < nks; t += TPB_G) {
      const int d = s_gk + t;
      if (d < KEPT_CAP) { kv[d] = lkv[t]; ki[d] = lki[t]; }
    }
    for (int t = tid; t < ncs; t += TPB_G) {
      const int d = s_gc + t;
      if (d < CAND_CAP) { cv[d] = lcv[t]; ci[d] = lci[t]; }
    }
  }
}

// ---------------- kernel 3: per-row select + sort + sample ------------------------
// mode: 0 = no ws (monolithic), 1 = ws hist only (old path), 2 = gather ran (fast)
extern "C" __global__ void __launch_bounds__(TPB_S) sampler_kernel(
    const float* __restrict__ logits, const float* __restrict__ temps,
    const void* __restrict__ topks_raw, const float* __restrict__ topps,
    const float* __restrict__ minps, const float* __restrict__ uarr,
    int* __restrict__ out, const int* __restrict__ ws_hist,
    const float* __restrict__ ws_max, const int* __restrict__ kept_cnt,
    const int* __restrict__ cand_cnt, const float* __restrict__ kept_val_g,
    const int* __restrict__ kept_idx_g, const float* __restrict__ cand_val_g,
    const int* __restrict__ cand_idx_g, int mode, int V, int B) {
  const int row = blockIdx.x;
  const int tid = threadIdx.x;

  __shared__ float cand[CAND_CAP];
  __shared__ int hist[NB];
  __shared__ int cand_idx[CAND_CAP];
  __shared__ int kept_idx[KEPT_CAP];
  __shared__ float kept_val[KEPT_CAP];
  __shared__ double sred[NW_S], sred2[NW_S];
  __shared__ int sredi[NW_S];
  __shared__ float sredf[NW_S];
  __shared__ double s_outd;
  __shared__ int s_outi;
  __shared__ int s_bad;
  __shared__ float lev_lo[MAXLEV], lev_sc[MAXLEV];
  __shared__ int lev_bin[MAXLEV];
  __shared__ int s_nlev, s_bin, s_kk, s_cntbin, s_cnt, s_ccnt, s_pos;
  __shared__ float s_lmax, s_vkl, s_lo, s_sc;

  const float* lr = logits + (size_t)row * (size_t)V;
  const float T = temps[row];
  const float topp = topps[row];
  const float minp = minps[row];
  const float u = uarr[row];
  const int k = decode_k(topks_raw, row, B, V);
  const int V4 = ((V & 3) == 0) ? V : 0;
  const int haveWs = (mode >= 1) ? 1 : 0;

  int n1 = -1;
  float lmax = 0.0f;

  // ================= FAST PATH (mode 2): no row access, no hist ===============
  if (mode == 2) {
    const int nk = kept_cnt[row];          // true count of (bin > kbin)
    const int nc = cand_cnt[row];          // true count of (bin == kbin)
    const int kk0 = k - nk;                // within-bin rank of v_k (from top)
    if (nk <= KEPT_CAP && nc >= 1 && nc <= CAND_CAP && kk0 >= 1 && kk0 <= nc) {
      if (tid == 0) {
        float m = ws_max[row * NS];
#pragma unroll
        for (int p = 1; p < NS; p++) m = fmaxf(m, ws_max[row * NS + p]);
        s_lmax = m;
      }
      // load candidates into LDS
      for (int t = tid; t < nc; t += TPB_S) {
        cand[t] = cand_val_g[(size_t)row * CAND_CAP + t];
        cand_idx[t] = cand_idx_g[(size_t)row * CAND_CAP + t];
      }
      __syncthreads();
      // tie-aware rank select of v_k among candidates
      for (int t = tid; t < nc; t += TPB_S) {
        const float v = cand[t];
        int rank = 0;
        for (int j = 0; j < nc; j++) {
          const float cj = cand[j];
          rank += (cj > v) ? 1 : ((cj == v && j < t) ? 1 : 0);
        }
        if (rank == kk0 - 1) s_vkl = v;   // exactly one thread matches
      }
      __syncthreads();
      const float vkl = s_vkl;
      // load kept set, then append candidates >= v_k
      for (int t = tid; t < nk; t += TPB_S) {
        kept_val[t] = kept_val_g[(size_t)row * KEPT_CAP + t];
        kept_idx[t] = kept_idx_g[(size_t)row * KEPT_CAP + t];
      }
      if (tid == 0) s_cnt = nk;
      __syncthreads();
      for (int t = tid; t < nc; t += TPB_S) {
        const float v = cand[t];
        if (v >= vkl) {
          const int p = atomicAdd(&s_cnt, 1);
          if (p < KEPT_CAP) { kept_val[p] = v; kept_idx[p] = cand_idx[t]; }
        }
      }
      __syncthreads();
      n1 = (s_cnt < KEPT_CAP) ? s_cnt : KEPT_CAP;
      lmax = s_lmax;
    }
  }

  // ================= FALLBACK PATH (verified round-4 stages A–D) ==============
  if (n1 < 0) {
    // ---------- stage A: row max + fixed-bound histogram ----------
    if (haveWs) {
      for (int i = tid; i < NB; i += TPB_S) {
        int t = 0;
#pragma unroll
        for (int p = 0; p < NS; p++) t += ws_hist[(size_t)(row * NS + p) * NB + i];
        hist[i] = t;
      }
      if (tid == 0) {
        float m = ws_max[row * NS];
#pragma unroll
        for (int p = 1; p < NS; p++) m = fmaxf(m, ws_max[row * NS + p]);
        s_lmax = m;
      }
      __syncthreads();
    } else {
      for (int i = tid; i < NB; i += TPB_S) hist[i] = 0;
      __syncthreads();
      float mx = -FLT_MAX;
      ROW_LOOP(mx = fmaxf(mx, lv); atomicAdd(&hist[bin_of(lv, FLO, FSC)], 1););
      mx = wmax_f(mx);
      __syncthreads();
      if ((tid & 63) == 0) sredf[tid >> 6] = mx;
      __syncthreads();
      if (tid == 0) {
        float t = sredf[0];
        for (int i = 1; i < NW_S; i++) t = fmaxf(t, sredf[i]);
        s_lmax = t;
      }
      __syncthreads();
    }
    lmax = s_lmax;

    // ---------- stage B: locate bin of the k-th largest (refinement fallback) --
    if (tid == 0) {
      s_kk = k; s_nlev = 0; s_vkl = lmax; s_lo = FLO; s_sc = FSC;
    }
    __syncthreads();

    for (int lev = 0; lev < MAXLEV; lev++) {
      if (tid < 64) {
        const int l = tid;
        const int b0 = NB - (l + 1) * (NB / 64);
        int c = 0;
#pragma unroll
        for (int j = 0; j < NB / 64; j++) c += hist[b0 + j];
        int incl = c;
#pragma unroll
        for (int o = 1; o < 64; o <<= 1) {
          int t2 = __shfl_up(incl, o);
          if (l >= o) incl += t2;
        }
        const int pref = incl - c;
        const int kk = s_kk;
        if (pref < kk && kk <= pref + c) {
          int rem = kk - pref;
          for (int j = NB / 64 - 1; j >= 0; j--) {
            const int h = hist[b0 + j];
            if (rem <= h) { s_bin = b0 + j; s_cntbin = h; s_kk = rem; break; }
            rem -= h;
          }
        }
      }
      __syncthreads();
      if (tid == 0) {
        lev_lo[lev] = s_lo; lev_sc[lev] = s_sc; lev_bin[lev] = s_bin;
        s_nlev = lev + 1;
      }
      __syncthreads();
      if (s_cntbin <= CAND_CAP) break;
      const float nlo = s_lo + (float)s_bin / s_sc;
      const float nsc = s_sc * (float)NB;
      const bool degw = !((nlo + (float)NB / nsc) > nlo);
      if (lev + 1 >= MAXLEV || degw) break;
      __syncthreads();
      if (tid == 0) { s_lo = nlo; s_sc = nsc; }
      for (int i = tid; i < NB; i += TPB_S) hist[i] = 0;
      __syncthreads();
      const int nl = lev + 1;
      ROW_LOOP(
        bool memb = true;
        for (int L = 0; L < nl; L++) {
          if (bin_of(lv, lev_lo[L], lev_sc[L]) != lev_bin[L]) { memb = false; break; }
        }
        if (memb) atomicAdd(&hist[bin_of(lv, nlo, nsc)], 1););
      __syncthreads();
    }

    // ---------- stage C: fused gather (kept-direct + candidates) ----------
    if (tid == 0) { s_cnt = 0; s_ccnt = 0; }
    __syncthreads();
    {
      const int nl = s_nlev;
      ROW_LOOP(
        int cls = 2;
        for (int L = 0; L < nl; L++) {
          const int b = bin_of(lv, lev_lo[L], lev_sc[L]);
          if (b > lev_bin[L]) { cls = 1; break; }
          if (b < lev_bin[L]) { cls = 0; break; }
        }
        if (cls == 1) {
          int p = atomicAdd(&s_cnt, 1);
          if (p < KEPT_CAP) { kept_idx[p] = gi; kept_val[p] = lv; }
        } else if (cls == 2) {
          int p = atomicAdd(&s_ccnt, 1);
          if (p < CAND_CAP) { cand[p] = lv; cand_idx[p] = gi; }
        });
    }
    __syncthreads();

    // ---------- stage D: tie-aware rank select + append ----------
    {
      const int n = (s_ccnt < CAND_CAP) ? s_ccnt : CAND_CAP;
      int kkq = s_kk;
      if (kkq > n) kkq = n;
      for (int t = tid; t < n; t += TPB_S) {
        const float v = cand[t];
        int rank = 0;
        for (int j = 0; j < n; j++) {
          const float cj = cand[j];
          rank += (cj > v) ? 1 : ((cj == v && j < t) ? 1 : 0);
        }
        if (rank == kkq - 1) s_vkl = v;
      }
    }
    __syncthreads();
    const float vkl = s_vkl;
    {
      const int n = (s_ccnt < CAND_CAP) ? s_ccnt : CAND_CAP;
      for (int t = tid; t < n; t += TPB_S) {
        const float v = cand[t];
        if (v >= vkl) {
          int p = atomicAdd(&s_cnt, 1);
          if (p < KEPT_CAP) { kept_idx[p] = cand_idx[t]; kept_val[p] = v; }
        }
      }
    }
    __syncthreads();
    n1 = (s_cnt < KEPT_CAP) ? s_cnt : KEPT_CAP;
  }

  if (n1 <= 0) {  // unreachable with valid data
    if (tid == 0) out[row] = 0;
    return;
  }

  // ---------- logits -> probs (precise exp only for kept) ----------
  const float xmaxT = lmax / T;  // == max_i fl(l_i/T) (division by T>0 is monotone)
  double lsum = 0.0;
  for (int t = tid; t < n1; t += TPB_S) {
    const float x = kept_val[t] / T;
    const float w = expf(x - xmaxT);
    kept_val[t] = w;
    lsum += (double)w;
  }
  const float s1f = (float)blk_sum_d(lsum, sred, &s_outd);
  for (int t = tid; t < n1; t += TPB_S) kept_val[t] = kept_val[t] / s1f;

  // pad & hybrid sort descending by value (idx carried); M >= 128 for the
  // wave-local register phases
  int M = 128;
  while (M < n1) M <<= 1;
  __syncthreads();
  for (int t = n1 + tid; t < M; t += TPB_S) { kept_val[t] = -1.0f; kept_idx[t] = 0x7FFFFFFF; }
  __syncthreads();
  hybrid_sort_desc_f(kept_val, kept_idx, M);
  // sortedness check -> fallback to verified full bitonic on violation
  if (tid == 0) s_bad = 0;
  __syncthreads();
  for (int t = tid; t + 1 < M; t += TPB_S)
    if (kept_val[t] < kept_val[t + 1]) s_bad = 1;
  __syncthreads();
  if (s_bad) bitonic_desc_f(kept_val, kept_idx, M);

  // ---------- top-p: (excl cum < p) keeps a prefix; then >= p_thresh ----------
  const int C = (M + TPB_S - 1) / TPB_S;
  double cls0 = 0.0;
  for (int j = 0; j < C; j++) {
    const int p = tid * C + j;
    if (p < n1) cls0 += (double)kept_val[p];
  }
  const double excl0 = blk_exscan_d(cls0, sred, sred2);
  int lc = 0;
  {
    double run = excl0;
    for (int j = 0; j < C; j++) {
      const int p = tid * C + j;
      if (p < n1) {
        if (run < (double)topp) lc++;
        run += (double)kept_val[p];
      }
    }
  }
  const int cnt = blk_sum_i(lc, sredi, &s_outi);  // >= 1 always
  const float pthr = kept_val[cnt - 1];

  int ln2 = 0;
  double ls2 = 0.0;
  for (int j = 0; j < C; j++) {
    const int p = tid * C + j;
    if (p < n1) {
      const float v = kept_val[p];
      if (v >= pthr) { ln2++; ls2 += (double)v; }
    }
  }
  const int n2 = blk_sum_i(ln2, sredi, &s_outi);
  const float s2f = (float)blk_sum_d(ls2, sred, &s_outd);

  // ---------- min-p (survivors are a prefix in sorted order) ----------
  const float maxr = kept_val[0] / s2f;
  const float th4 = minp * maxr;
  int ln3 = 0;
  double ls3 = 0.0;
  for (int j = 0; j < C; j++) {
    const int p = tid * C + j;
    if (p < n2) {
      const float r = kept_val[p] / s2f;
      if (r >= th4) { ln3++; ls3 += (double)r; }
    }
  }
  const int n3 = blk_sum_i(ln3, sredi, &s_outi);
  const float s3f = (float)blk_sum_d(ls3, sred, &s_outd);

  // ---------- finalize probs, hybrid sort survivors by index, inverse-CDF ------
  int M3 = 128;
  while (M3 < n3) M3 <<= 1;
  __syncthreads();
  for (int t = tid; t < M3; t += TPB_S) {
    if (t < n3) {
      const float r = kept_val[t] / s2f;
      kept_val[t] = r / s3f;
    } else {
      kept_val[t] = 0.0f;
      kept_idx[t] = 0x7FFFFFFF;
    }
  }
  __syncthreads();
  hybrid_sort_asc_i(kept_idx, kept_val, M3);
  if (tid == 0) s_bad = 0;
  __syncthreads();
  for (int t = tid; t + 1 < M3; t += TPB_S)
    if (kept_idx[t] > kept_idx[t + 1]) s_bad = 1;
  __syncthreads();
  if (s_bad) bitonic_asc_i(kept_idx, kept_val, M3);

  const int C3 = (M3 + TPB_S - 1) / TPB_S;
  double cls3 = 0.0;
  for (int j = 0; j < C3; j++) {
    const int p = tid * C3 + j;
    if (p < n3) cls3 += (double)kept_val[p];
  }
  const double e5 = blk_exscan_d(cls3, sred, sred2);
  if (tid == 0) s_pos = 0x7FFFFFFF;
  __syncthreads();
  {
    double run = e5;
    int found = -1;
    for (int j = 0; j < C3; j++) {
      const int p = tid * C3 + j;
      if (p < n3) {
        run += (double)kept_val[p];
        if (run >= (double)u) { found = p; break; }
      }
    }
    if (found >= 0) atomicMin(&s_pos, found);
  }
  __syncthreads();
  if (tid == 0) {
    int token;
    if (!(u > 0.0f)) token = 0;                   // all cdf >= 0 == u -> count 0
    else if (s_pos == 0x7FFFFFFF) token = V - 1;  // u beyond total mass -> clip
    else token = kept_idx[s_pos];                 // == count of cdf entries < u
    out[row] = token;
  }
}

extern "C" void kernel_launch(void* const* d_in, const int* in_sizes, int n_in,
                              void* d_out, int out_size, void* d_ws, size_t ws_size,
                              hipStream_t stream) {
  const float* logits = (const float*)d_in[0];
  const float* temps = (const float*)d_in[1];
  const void* topks = d_in[2];
  const float* topps = (const float*)d_in[3];
  const float* minps = (const float*)d_in[4];
  const float* u = (const float*)d_in[5];
  int* out = (int*)d_out;
  const int B = in_sizes[1];
  const int V = in_sizes[0] / B;
  (void)n_in; (void)out_size;

  // ws layout
  char* p = (char*)d_ws;
  int* ws_hist = (int*)p;        p += (size_t)NS * B * NB * sizeof(int);
  float* ws_max = (float*)p;     p += (size_t)NS * B * sizeof(float);
  int* kept_cnt = (int*)p;       p += (size_t)B * sizeof(int);
  int* cand_cnt = (int*)p;       p += (size_t)B * sizeof(int);
  float* kept_val_g = (float*)p; p += (size_t)B * KEPT_CAP * sizeof(float);
  int* kept_idx_g = (int*)p;     p += (size_t)B * KEPT_CAP * sizeof(int);
  float* cand_val_g = (float*)p; p += (size_t)B * CAND_CAP * sizeof(float);
  int* cand_idx_g = (int*)p;     p += (size_t)B * CAND_CAP * sizeof(int);
  const size_t need_full = (size_t)(p - (char*)d_ws);
  const size_t need_hist = (size_t)NS * B * NB * sizeof(int) + (size_t)NS * B * sizeof(float);

  int mode = 0;
  if (d_ws && ws_size >= need_full) mode = 2;
  else if (d_ws && ws_size >= need_hist) mode = 1;

  if (mode >= 1) {
    hist_max_kernel<<<dim3(B * NS), dim3(TPB_H), 0, stream>>>(
        logits, V, ws_hist, ws_max, kept_cnt, cand_cnt, (mode == 2) ? 1 : 0);
  }
  if (mode == 2) {
    gather_kernel<<<dim3(B * NS), dim3(TPB_G), 0, stream>>>(
        logits, topks, V, B, ws_hist, kept_cnt, cand_cnt,
        kept_val_g, kept_idx_g, cand_val_g, cand_idx_g);
  }
  sampler_kernel<<<dim3(B), dim3(TPB_S), 0, stream>>>(
      logits, temps, topks, topps, minps, u, out, ws_hist, ws_max,
      kept_cnt, cand_cnt, kept_val_g, kept_idx_g, cand_val_g, cand_idx_g,
      mode, V, B);
}